// Round 4
// baseline (179.731 us; speedup 1.0000x reference)
//
#include <hip/hip_runtime.h>

#define BN 200
#define VN 64
#define HIDD 64
#define FINN 32
#define NSW 10
#define EC 63
#define MNE 73
#define NEDGE 146
#define NPACK 128

typedef unsigned short u16;
typedef unsigned int u32;
typedef __attribute__((ext_vector_type(8))) short bf16x8;
typedef __attribute__((ext_vector_type(4))) float f32x4;

__device__ __forceinline__ float bfu(u16 u) { return __uint_as_float(((u32)u) << 16); }
__device__ __forceinline__ u16 f2bf(float f) {
    u32 x = __float_as_uint(f);
    u32 r = x + 0x7fffu + ((x >> 16) & 1u);
    return (u16)(r >> 16);
}
__device__ __forceinline__ float cvtv(const void* p, int i, int fl) {
    return fl ? bfu(((const u16*)p)[i]) : ((const float*)p)[i];
}

// XOR swizzle: spread 8-elem (16B) column groups across banks by row
__device__ __forceinline__ int swz(int row, int col) { return col ^ ((row & 7) << 3); }

// packed hi/lo bf16 load/store (value = hi + lo)
__device__ __forceinline__ float ldp(const u16* H, const u16* L, int idx) {
    return bfu(H[idx]) + bfu(L[idx]);
}
__device__ __forceinline__ void stp(u16* H, u16* L, int idx, float f) {
    u16 h = f2bf(f);
    H[idx] = h;
    L[idx] = f2bf(f - bfu(h));
}

// 2-way interleaved LayerNorm+ReLU (two independent shuffle trees in flight)
__device__ __forceinline__ void ln2(float ea, float eb, float& ra, float& rb) {
    float a1 = ea, a2 = ea * ea, b1 = eb, b2 = eb * eb;
#pragma unroll
    for (int m = 1; m < 64; m <<= 1) {
        a1 += __shfl_xor(a1, m);
        a2 += __shfl_xor(a2, m);
        b1 += __shfl_xor(b1, m);
        b2 += __shfl_xor(b2, m);
    }
    float ma = a1 * 0.015625f, mb = b1 * 0.015625f;
    float va = fmaxf(a2 * 0.015625f - ma * ma, 0.f);
    float vb = fmaxf(b2 * 0.015625f - mb * mb, 0.f);
    ra = fmaxf((ea - ma) * rsqrtf(va + 1e-5f), 0.f);
    rb = fmaxf((eb - mb) * rsqrtf(vb + 1e-5f), 0.f);
}

// 4-way interleaved LayerNorm+ReLU
__device__ __forceinline__ void ln4(float ea, float eb, float ec, float ed,
                                    float& ra, float& rb, float& rc, float& rd) {
    float a1 = ea, a2 = ea * ea, b1 = eb, b2 = eb * eb;
    float c1 = ec, c2 = ec * ec, d1 = ed, d2 = ed * ed;
#pragma unroll
    for (int m = 1; m < 64; m <<= 1) {
        a1 += __shfl_xor(a1, m); a2 += __shfl_xor(a2, m);
        b1 += __shfl_xor(b1, m); b2 += __shfl_xor(b2, m);
        c1 += __shfl_xor(c1, m); c2 += __shfl_xor(c2, m);
        d1 += __shfl_xor(d1, m); d2 += __shfl_xor(d2, m);
    }
    float ma = a1 * 0.015625f, mb = b1 * 0.015625f;
    float mc = c1 * 0.015625f, md = d1 * 0.015625f;
    float va = fmaxf(a2 * 0.015625f - ma * ma, 0.f);
    float vb = fmaxf(b2 * 0.015625f - mb * mb, 0.f);
    float vc = fmaxf(c2 * 0.015625f - mc * mc, 0.f);
    float vd = fmaxf(d2 * 0.015625f - md * md, 0.f);
    ra = fmaxf((ea - ma) * rsqrtf(va + 1e-5f), 0.f);
    rb = fmaxf((eb - mb) * rsqrtf(vb + 1e-5f), 0.f);
    rc = fmaxf((ec - mc) * rsqrtf(vc + 1e-5f), 0.f);
    rd = fmaxf((ed - md) * rsqrtf(vd + 1e-5f), 0.f);
}

struct CvtArgs { const void* src[21]; };

// ======== prep: block 0 = topology/ews/dinv/sw_eidx/inc-lists (LDS-staged);
//          blocks 1..NPACK = bf16 hi/lo MFMA-B packing of ALL weights ========
__global__ __launch_bounds__(256) void k_prep(CvtArgs ca, const int* __restrict__ eA,
                                              const int* __restrict__ eS,
                                              u16* __restrict__ c1h, u16* __restrict__ c1l,
                                              u16* __restrict__ c2h, u16* __restrict__ c2l,
                                              u16* __restrict__ s1h, u16* __restrict__ s1l,
                                              u16* __restrict__ s2h, u16* __restrict__ s2l,
                                              u16* __restrict__ w0h, u16* __restrict__ w0l,
                                              u16* __restrict__ wlh, u16* __restrict__ wll,
                                              float* __restrict__ ews, float* __restrict__ dinv,
                                              int* __restrict__ row_ptr, int* __restrict__ colp,
                                              int* __restrict__ sw_eidx,
                                              float* __restrict__ dinvD, int* __restrict__ incCnt,
                                              int* __restrict__ incM) {
    int t = threadIdx.x;
    int fl = (((const u16*)ca.src[1])[1] == 0x3F80) ? 1 : 0;
    if (blockIdx.x == 0) {
        __shared__ unsigned char flagL[64 * 65];   // bit0 = conn!=0, bit1 = S!=0
        __shared__ float wsL[FINN * 64];
        __shared__ float emL[64];
        __shared__ int degL[64], rpS[65], colS[NEDGE + 16];
        __shared__ int eAL[2 * EC], eSL[2 * NSW];

        if (t < 2 * EC) eAL[t] = eA[t];
        if (t >= 128 && t < 128 + 2 * NSW) eSL[t - 128] = eS[t - 128];
        if (t >= 160 && t < 224) emL[t - 160] = cvtv(ca.src[3], t - 160, fl);
        for (int i = t; i < FINN * 64; i += 256) wsL[i] = cvtv(ca.src[4], i, fl);
        for (int i = t; i < 4096; i += 256) {
            float a = cvtv(ca.src[1], i, fl);
            float s = cvtv(ca.src[2], i, fl);
            int r = i >> 6, c = i & 63;
            flagL[r * 65 + c] = (unsigned char)(((a != 0.f || s != 0.f) ? 1 : 0) |
                                                ((s != 0.f) ? 2 : 0));
        }
        __syncthreads();

        if (t < 128) {
            int j = t >> 6, k = t & 63;
            float a = 0.f;
#pragma unroll
            for (int h = 0; h < FINN; h++) a += emL[j * FINN + h] * wsL[h * 64 + k];
            ews[(j << 6) + k] = a;
        }
        if (t < 64) {
            int d = 0;
#pragma unroll
            for (int w = 0; w < 64; w++) d += flagL[t * 65 + w] & 1;
            degL[t] = d;
            dinv[t] = 1.f / fmaxf((float)d, 1.f);
        }
        __syncthreads();
        if (t == 0) {
            int c = 0;
            for (int v = 0; v < 64; v++) { rpS[v] = c; c += degL[v]; }
            rpS[64] = c;
        }
        __syncthreads();
        if (t < 65) row_ptr[t] = rpS[t];
        if (t < 64) {
            int pos = rpS[t];
#pragma unroll
            for (int w = 0; w < 64; w++) {
                int f = flagL[t * 65 + w];
                if (f & 1) colS[pos++] = w | ((f & 2) ? 256 : 0) | (t << 16);
            }
        }
        __syncthreads();
        int tot = rpS[64];
        if (t < tot) colp[t] = colS[t];
        if (t < NSW) {
            int si = eSL[t], sj = eSL[NSW + t];
            int idx = 0;
            for (int e = rpS[si]; e < rpS[si + 1]; e++)
                if ((colS[e] & 255) == sj) idx = e;
            sw_eidx[t] = idx;
        }
        if (t < 64) {
            dinvD[t] = cvtv(ca.src[18], t * 64 + t, fl);
            int cnt = 0;
            for (int m = 0; m < MNE; m++) {
                int par = (m < EC) ? eAL[m] : eSL[m - EC];
                int chi = (m < EC) ? eAL[EC + m] : eSL[NSW + (m - EC)];
                if (par == t && cnt < 8) incM[t * 8 + cnt++] = (m << 1);
                if (chi == t && cnt < 8) incM[t * 8 + cnt++] = (m << 1) | 1;
            }
            incCnt[t] = cnt;
        }
    } else {
        const int T1 = 36864, T2 = T1 + 3072, T3 = T2 + 65536, T4 = T3 + 4096;
        const int T5 = T4 + 8192, TOT = T5 + 40960;
        for (int i = (blockIdx.x - 1) * 256 + t; i < TOT; i += NPACK * 256) {
            int idx = i;
            const void* src;
            u16 *dh, *dl;
            int K2, N2, nt, rem, loff = 0;
            if (idx < T1) {
                nt = idx / 3072; rem = idx - nt * 3072; src = ca.src[16];
                dh = c1h + idx; dl = c1l + idx; K2 = 192; N2 = 192;
            } else if (idx < T2) {
                idx -= T1; nt = 0; rem = idx; src = ca.src[17];
                dh = c2h + idx; dl = c2l + idx; K2 = 192; N2 = 3;
            } else if (idx < T3) {
                idx -= T2; nt = idx >> 12; rem = idx & 4095; src = ca.src[14];
                dh = s1h + idx; dl = s1l + idx; K2 = 256; N2 = 256;
            } else if (idx < T4) {
                idx -= T3; nt = 0; rem = idx; src = ca.src[15];
                dh = s2h + idx; dl = s2l + idx; K2 = 256; N2 = 4;
            } else if (idx < T5) {
                int j = idx - T4;
                int mt = j >> 11;             // 0=Wi 1=Wj 2=U 3=V  (src 5..8)
                int m2 = j & 2047;
                nt = m2 >> 9; rem = m2 & 511; src = ca.src[5 + mt];
                dh = w0h + j; dl = w0l + j; K2 = 32; N2 = 64;
            } else {
                int j = idx - T5;
                int l = j / 20480;
                int jj = j - l * 20480;
                int mt = jj >> 12;            // 0=Ws 1=Wi 2=Wj 3=U 4=V (src 9..13)
                int m2 = jj & 4095;
                nt = m2 >> 10; rem = m2 & 1023; src = ca.src[9 + mt];
                loff = l * 4096;
                dh = wlh + j; dl = wll + j; K2 = 64; N2 = 64;
            }
            int kb = rem >> 9, r8 = rem & 511, ln = r8 >> 3, jq = r8 & 7;
            int k = kb * 32 + ((ln >> 4) << 3) + jq;
            int n = nt * 16 + (ln & 15);
            float val = 0.f;
            if (n < N2 && k < K2) val = cvtv(src, loff + k * N2 + n, fl);
            u16 h = f2bf(val);
            *dh = h;
            *dl = f2bf(val - bfu(h));
        }
    }
}

// tLs quadrants (match w0 pack mat order: Wi,Wj,U,V)
#define XI 0
#define XJ 1
#define XU 2
#define XV 3

// ======== fused whole-model kernel: one block per batch element, all state in LDS ========
__global__ __launch_bounds__(1024) void k_main(
    const void* __restrict__ xraw, const u16* __restrict__ A_u16,
    const int* __restrict__ eA, const int* __restrict__ eS,
    const float* __restrict__ ews, const float* __restrict__ dinv,
    const int* __restrict__ row_ptr, const int* __restrict__ colp,
    const int* __restrict__ sw_eidx,
    const float* __restrict__ dinvD, const int* __restrict__ incCnt, const int* __restrict__ incM,
    const u16* __restrict__ w0h, const u16* __restrict__ w0l,
    const u16* __restrict__ wlh, const u16* __restrict__ wll,
    const u16* __restrict__ c1h, const u16* __restrict__ c1l,
    const u16* __restrict__ c2h, const u16* __restrict__ c2l,
    const u16* __restrict__ s1h, const u16* __restrict__ s1l,
    const u16* __restrict__ s2h, const u16* __restrict__ s2l,
    void* __restrict__ out_v)
{
    __shared__ __align__(16) u16 xHp[64 * 64], xLp[64 * 64];         // node features
    __shared__ __align__(16) u16 sHp[NEDGE * 64], sLp[NEDGE * 64];   // edge states
    __shared__ __align__(16) float preL[NEDGE * 64];                 // s@Ws pre-act / gate*xv
    __shared__ __align__(16) float tLs[4 * 64 * 64];                 // xi/xj/xu/xv; heads: hid overlay
    __shared__ __align__(16) u16 xgH[64], xgLo[64];
    __shared__ float ewsL[128];
    __shared__ float dinvL[64];
    __shared__ int rpL[65];
    __shared__ int colL[NEDGE + 6];
    __shared__ int swLx[NSW];
    __shared__ int eALs[2 * EC], eSLs[2 * NSW];
    __shared__ float cmoL[EC * 3], smoL[NSW * 4];

    int b = blockIdx.x, t = threadIdx.x;
    int lane = t & 63, wid = t >> 6;          // 16 waves
    int m = lane & 15, quad = lane >> 4;
    int fl = (A_u16[1] == 0x3F80) ? 1 : 0;

    // ---- stage ----
    for (int i = t; i < 2048; i += 1024) {
        int r = i >> 5, c = i & 31;
        stp(xHp, xLp, (r << 6) + swz(r, c), cvtv(xraw, b * 2048 + i, fl));
    }
    if (t < 128) ewsL[t] = ews[t];
    if (t < 64) dinvL[t] = dinv[t];
    if (t < 65) rpL[t] = row_ptr[t];
    if (t < NEDGE) colL[t] = colp[t];
    if (t < NSW) swLx[t] = sw_eidx[t];
    if (t >= 256 && t < 256 + 2 * EC) eALs[t - 256] = eA[t - 256];
    if (t >= 512 && t < 512 + 2 * NSW) eSLs[t - 512] = eS[t - 512];
    __syncthreads();

    // ---- layer 0 transforms: x(64x32) @ {Wi,Wj,U,V}(32x64) ----
    {
        int mat = wid >> 2, Mt = wid & 3;
        const u16* bhp = w0h + mat * 2048;
        const u16* blp = w0l + mat * 2048;
        int row = Mt * 16 + m;
        int c0 = quad * 8;
        bf16x8 ah = *(const bf16x8*)&xHp[(row << 6) + swz(row, c0)];
        bf16x8 al = *(const bf16x8*)&xLp[(row << 6) + swz(row, c0)];
        f32x4 acc[4];
#pragma unroll
        for (int nt = 0; nt < 4; nt++) acc[nt] = (f32x4){0.f, 0.f, 0.f, 0.f};
#pragma unroll
        for (int nt = 0; nt < 4; nt++) {
            int o = (nt << 9) + (lane << 3);
            bf16x8 bh = *(const bf16x8*)(bhp + o);
            bf16x8 bl = *(const bf16x8*)(blp + o);
            acc[nt] = __builtin_amdgcn_mfma_f32_16x16x32_bf16(ah, bh, acc[nt], 0, 0, 0);
            acc[nt] = __builtin_amdgcn_mfma_f32_16x16x32_bf16(al, bh, acc[nt], 0, 0, 0);
            acc[nt] = __builtin_amdgcn_mfma_f32_16x16x32_bf16(ah, bl, acc[nt], 0, 0, 0);
        }
#pragma unroll
        for (int nt = 0; nt < 4; nt++)
#pragma unroll
            for (int r = 0; r < 4; r++) {
                int orow = Mt * 16 + quad * 4 + r;
                tLs[mat * 4096 + (orow << 6) + swz(orow, nt * 16 + m)] = acc[nt][r];
            }
    }
    __syncthreads();

    // ---- layer 0 B1: edge-parallel ----
    for (int e = wid; e < NEDGE; e += 32) {
        int e2i = e + 16;
        int has2 = (e2i < NEDGE);
        int eb2 = has2 ? e2i : e;
        int cpa = colL[e], cpb = colL[eb2];
        int wa = cpa & 255, va = (cpa >> 16) & 255;
        int wb = cpb & 255, vb = (cpb >> 16) & 255;
        int sia = (e << 6) + swz(e, lane);
        int sib = (eb2 << 6) + swz(eb2, lane);
        float eea = ewsL[(((cpa >> 8) & 1) << 6) + lane]
                  + tLs[XI * 4096 + (va << 6) + swz(va, lane)]
                  + tLs[XJ * 4096 + (wa << 6) + swz(wa, lane)];
        float eeb = ewsL[(((cpb >> 8) & 1) << 6) + lane]
                  + tLs[XI * 4096 + (vb << 6) + swz(vb, lane)]
                  + tLs[XJ * 4096 + (wb << 6) + swz(wb, lane)];
        float ha, hb;
        ln2(eea, eeb, ha, hb);
        stp(sHp, sLp, sia, ha);
        preL[sia] = tLs[XV * 4096 + (wa << 6) + swz(wa, lane)]
                  * __fdividef(1.f, 1.f + __expf(-ha));
        if (has2) {
            stp(sHp, sLp, sib, hb);
            preL[sib] = tLs[XV * 4096 + (wb << 6) + swz(wb, lane)]
                      * __fdividef(1.f, 1.f + __expf(-hb));
        }
    }
    __syncthreads();

    // ---- layer 0 B2: per-v aggregation ----
    {
        int v0 = wid << 2;
        float mc0 = 0.f, mc1 = 0.f, mc2 = 0.f, mc3 = 0.f;
        for (int e = rpL[v0]; e < rpL[v0 + 1]; e++) mc0 += preL[(e << 6) + swz(e, lane)];
        for (int e = rpL[v0 + 1]; e < rpL[v0 + 2]; e++) mc1 += preL[(e << 6) + swz(e, lane)];
        for (int e = rpL[v0 + 2]; e < rpL[v0 + 3]; e++) mc2 += preL[(e << 6) + swz(e, lane)];
        for (int e = rpL[v0 + 3]; e < rpL[v0 + 4]; e++) mc3 += preL[(e << 6) + swz(e, lane)];
        float z0 = tLs[XU * 4096 + ((v0 + 0) << 6) + swz(v0 + 0, lane)] + mc0 * dinvL[v0 + 0];
        float z1 = tLs[XU * 4096 + ((v0 + 1) << 6) + swz(v0 + 1, lane)] + mc1 * dinvL[v0 + 1];
        float z2 = tLs[XU * 4096 + ((v0 + 2) << 6) + swz(v0 + 2, lane)] + mc2 * dinvL[v0 + 2];
        float z3 = tLs[XU * 4096 + ((v0 + 3) << 6) + swz(v0 + 3, lane)] + mc3 * dinvL[v0 + 3];
        float h0, h1, h2, h3;
        ln4(z0, z1, z2, z3, h0, h1, h2, h3);
        stp(xHp, xLp, ((v0 + 0) << 6) + swz(v0 + 0, lane), h0);
        stp(xHp, xLp, ((v0 + 1) << 6) + swz(v0 + 1, lane), h1);
        stp(xHp, xLp, ((v0 + 2) << 6) + swz(v0 + 2, lane), h2);
        stp(xHp, xLp, ((v0 + 3) << 6) + swz(v0 + 3, lane), h3);
    }
    __syncthreads();

    // ---- layers 1,2 ----
    for (int l = 0; l < 2; l++) {
        // (a) x-GEMMs (16 waves) + s-GEMM (40 units over 16 waves)
        {
            int mat = wid >> 2, Mt = wid & 3;
            const u16* bhp = wlh + l * 20480 + (mat + 1) * 4096;
            const u16* blp = wll + l * 20480 + (mat + 1) * 4096;
            int row = Mt * 16 + m;
            f32x4 acc[4];
#pragma unroll
            for (int nt = 0; nt < 4; nt++) acc[nt] = (f32x4){0.f, 0.f, 0.f, 0.f};
#pragma unroll
            for (int kb = 0; kb < 2; kb++) {
                int c0 = kb * 32 + quad * 8;
                bf16x8 ah = *(const bf16x8*)&xHp[(row << 6) + swz(row, c0)];
                bf16x8 al = *(const bf16x8*)&xLp[(row << 6) + swz(row, c0)];
#pragma unroll
                for (int nt = 0; nt < 4; nt++) {
                    int o = (((nt << 1) + kb) << 9) + (lane << 3);
                    bf16x8 bh = *(const bf16x8*)(bhp + o);
                    bf16x8 bl = *(const bf16x8*)(blp + o);
                    acc[nt] = __builtin_amdgcn_mfma_f32_16x16x32_bf16(ah, bh, acc[nt], 0, 0, 0);
                    acc[nt] = __builtin_amdgcn_mfma_f32_16x16x32_bf16(al, bh, acc[nt], 0, 0, 0);
                    acc[nt] = __builtin_amdgcn_mfma_f32_16x16x32_bf16(ah, bl, acc[nt], 0, 0, 0);
                }
            }
#pragma unroll
            for (int nt = 0; nt < 4; nt++)
#pragma unroll
                for (int r = 0; r < 4; r++) {
                    int orow = Mt * 16 + quad * 4 + r;
                    tLs[mat * 4096 + (orow << 6) + swz(orow, nt * 16 + m)] = acc[nt][r];
                }

            const u16* sbh = wlh + l * 20480;   // Ws
            const u16* sbl = wll + l * 20480;
            for (int u = wid; u < 40; u += 16) {
                int rt = u >> 2, ntq = u & 3;
                int srow = rt * 16 + m;
                int ar = (srow > NEDGE - 1) ? (NEDGE - 1) : srow;
                f32x4 sacc = (f32x4){0.f, 0.f, 0.f, 0.f};
#pragma unroll
                for (int kb = 0; kb < 2; kb++) {
                    int c0 = kb * 32 + quad * 8;
                    bf16x8 ah = *(const bf16x8*)&sHp[(ar << 6) + swz(ar, c0)];
                    bf16x8 al = *(const bf16x8*)&sLp[(ar << 6) + swz(ar, c0)];
                    int o = (((ntq << 1) + kb) << 9) + (lane << 3);
                    bf16x8 bh = *(const bf16x8*)(sbh + o);
                    bf16x8 bl = *(const bf16x8*)(sbl + o);
                    sacc = __builtin_amdgcn_mfma_f32_16x16x32_bf16(ah, bh, sacc, 0, 0, 0);
                    sacc = __builtin_amdgcn_mfma_f32_16x16x32_bf16(al, bh, sacc, 0, 0, 0);
                    sacc = __builtin_amdgcn_mfma_f32_16x16x32_bf16(ah, bl, sacc, 0, 0, 0);
                }
#pragma unroll
                for (int r = 0; r < 4; r++) {
                    int orow = rt * 16 + quad * 4 + r;
                    if (orow < NEDGE)
                        preL[(orow << 6) + swz(orow, ntq * 16 + m)] = sacc[r];
                }
            }
        }
        __syncthreads();

        // (b1) edge-parallel update
        for (int e = wid; e < NEDGE; e += 32) {
            int e2i = e + 16;
            int has2 = (e2i < NEDGE);
            int eb2 = has2 ? e2i : e;
            int cpa = colL[e], cpb = colL[eb2];
            int wa = cpa & 255, va = (cpa >> 16) & 255;
            int wb = cpb & 255, vb = (cpb >> 16) & 255;
            int sia = (e << 6) + swz(e, lane);
            int sib = (eb2 << 6) + swz(eb2, lane);
            float eea = preL[sia]
                      + tLs[XI * 4096 + (va << 6) + swz(va, lane)]
                      + tLs[XJ * 4096 + (wa << 6) + swz(wa, lane)];
            float eeb = preL[sib]
                      + tLs[XI * 4096 + (vb << 6) + swz(vb, lane)]
                      + tLs[XJ * 4096 + (wb << 6) + swz(wb, lane)];
            float ha, hb;
            ln2(eea, eeb, ha, hb);
            float souta = ldp(sHp, sLp, sia) + ha;
            float soutb = ldp(sHp, sLp, sib) + hb;
            stp(sHp, sLp, sia, souta);
            preL[sia] = tLs[XV * 4096 + (wa << 6) + swz(wa, lane)]
                      * __fdividef(1.f, 1.f + __expf(-souta));
            if (has2) {
                stp(sHp, sLp, sib, soutb);
                preL[sib] = tLs[XV * 4096 + (wb << 6) + swz(wb, lane)]
                          * __fdividef(1.f, 1.f + __expf(-soutb));
            }
        }
        __syncthreads();

        // (b2) per-v aggregation + node update (+ xg partial on last layer)
        {
            int v0 = wid << 2;
            float mc0 = 0.f, mc1 = 0.f, mc2 = 0.f, mc3 = 0.f;
            for (int e = rpL[v0]; e < rpL[v0 + 1]; e++) mc0 += preL[(e << 6) + swz(e, lane)];
            for (int e = rpL[v0 + 1]; e < rpL[v0 + 2]; e++) mc1 += preL[(e << 6) + swz(e, lane)];
            for (int e = rpL[v0 + 2]; e < rpL[v0 + 3]; e++) mc2 += preL[(e << 6) + swz(e, lane)];
            for (int e = rpL[v0 + 3]; e < rpL[v0 + 4]; e++) mc3 += preL[(e << 6) + swz(e, lane)];
            float z0 = tLs[XU * 4096 + ((v0 + 0) << 6) + swz(v0 + 0, lane)] + mc0 * dinvL[v0 + 0];
            float z1 = tLs[XU * 4096 + ((v0 + 1) << 6) + swz(v0 + 1, lane)] + mc1 * dinvL[v0 + 1];
            float z2 = tLs[XU * 4096 + ((v0 + 2) << 6) + swz(v0 + 2, lane)] + mc2 * dinvL[v0 + 2];
            float z3 = tLs[XU * 4096 + ((v0 + 3) << 6) + swz(v0 + 3, lane)] + mc3 * dinvL[v0 + 3];
            float h0, h1, h2, h3;
            ln4(z0, z1, z2, z3, h0, h1, h2, h3);
            int i0 = ((v0 + 0) << 6) + swz(v0 + 0, lane);
            int i1 = ((v0 + 1) << 6) + swz(v0 + 1, lane);
            int i2 = ((v0 + 2) << 6) + swz(v0 + 2, lane);
            int i3 = ((v0 + 3) << 6) + swz(v0 + 3, lane);
            float x0 = ldp(xHp, xLp, i0) + h0;
            float x1 = ldp(xHp, xLp, i1) + h1;
            float x2 = ldp(xHp, xLp, i2) + h2;
            float x3 = ldp(xHp, xLp, i3) + h3;
            stp(xHp, xLp, i0, x0);
            stp(xHp, xLp, i1, x1);
            stp(xHp, xLp, i2, x2);
            stp(xHp, xLp, i3, x3);
            if (l == 1) tLs[(wid << 6) + lane] = x0 + x1 + x2 + x3;   // xg partial
        }
        __syncthreads();
    }

    // ---- xg final ----
    if (t < 64) {
        float s = 0.f;
#pragma unroll
        for (int i = 0; i < 16; i++) s += tLs[(i << 6) + t];
        stp(xgH, xgLo, t, s);
    }
    __syncthreads();

    // ======== heads ========
    u16* tp  = (u16*)tLs;
    u16* hcH = tp;                  // 64 x 192
    u16* hcL = tp + 12288;
    u16* hsH = tp + 24576;          // 16 x 256
    u16* hsL = tp + 28672;

    // ---- H2: cmlp GEMM1 (waves 0-11) ∥ smlp GEMM1 (waves 12-15) ----
    if (wid < 12) {
        int Mt = wid & 3, ntg = wid >> 2;
        int e = Mt * 16 + m; if (e > 62) e = 62;
        int ai = eALs[e], aj = eALs[EC + e];
        f32x4 acc[4];
#pragma unroll
        for (int j = 0; j < 4; j++) acc[j] = (f32x4){0.f, 0.f, 0.f, 0.f};
#pragma unroll
        for (int kb = 0; kb < 6; kb++) {
            int k = kb * 32 + quad * 8;
            bf16x8 ah, al;
            if (k < 64) {
                ah = *(const bf16x8*)&xHp[(ai << 6) + swz(ai, k)];
                al = *(const bf16x8*)&xLp[(ai << 6) + swz(ai, k)];
            } else if (k < 128) {
                int c = k - 64;
                ah = *(const bf16x8*)&xHp[(aj << 6) + swz(aj, c)];
                al = *(const bf16x8*)&xLp[(aj << 6) + swz(aj, c)];
            } else {
                int c = k - 128;
                ah = *(const bf16x8*)&xgH[c];
                al = *(const bf16x8*)&xgLo[c];
            }
#pragma unroll
            for (int j = 0; j < 4; j++) {
                int nt = ntg * 4 + j;
                int o = ((nt * 6 + kb) << 9) + (lane << 3);
                bf16x8 bh = *(const bf16x8*)(c1h + o);
                bf16x8 bl = *(const bf16x8*)(c1l + o);
                acc[j] = __builtin_amdgcn_mfma_f32_16x16x32_bf16(ah, bh, acc[j], 0, 0, 0);
                acc[j] = __builtin_amdgcn_mfma_f32_16x16x32_bf16(al, bh, acc[j], 0, 0, 0);
                acc[j] = __builtin_amdgcn_mfma_f32_16x16x32_bf16(ah, bl, acc[j], 0, 0, 0);
            }
        }
#pragma unroll
        for (int j = 0; j < 4; j++) {
            int nt = ntg * 4 + j;
#pragma unroll
            for (int r = 0; r < 4; r++) {
                int row = Mt * 16 + quad * 4 + r;
                stp(hcH, hcL, row * 192 + swz(row, nt * 16 + m), fmaxf(acc[j][r], 0.f));
            }
        }
    } else {
        int e2 = (m > 9) ? 9 : m;
        int si = eSLs[e2], sj = eSLs[NSW + e2];
        int sw = swLx[e2];
#pragma unroll
        for (int j = 0; j < 4; j++) {
            int nt = (wid - 12) * 4 + j;
            f32x4 accS = (f32x4){0.f, 0.f, 0.f, 0.f};
#pragma unroll
            for (int kb = 0; kb < 8; kb++) {
                int k = kb * 32 + quad * 8;
                bf16x8 ah, al;
                if (k < 64) {
                    ah = *(const bf16x8*)&sHp[(sw << 6) + swz(sw, k)];
                    al = *(const bf16x8*)&sLp[(sw << 6) + swz(sw, k)];
                } else if (k < 128) {
                    int c = k - 64;
                    ah = *(const bf16x8*)&xHp[(si << 6) + swz(si, c)];
                    al = *(const bf16x8*)&xLp[(si << 6) + swz(si, c)];
                } else if (k < 192) {
                    int c = k - 128;
                    ah = *(const bf16x8*)&xHp[(sj << 6) + swz(sj, c)];
                    al = *(const bf16x8*)&xLp[(sj << 6) + swz(sj, c)];
                } else {
                    int c = k - 192;
                    ah = *(const bf16x8*)&xgH[c];
                    al = *(const bf16x8*)&xgLo[c];
                }
                int o = ((nt * 8 + kb) << 9) + (lane << 3);
                bf16x8 bh = *(const bf16x8*)(s1h + o);
                bf16x8 bl = *(const bf16x8*)(s1l + o);
                accS = __builtin_amdgcn_mfma_f32_16x16x32_bf16(ah, bh, accS, 0, 0, 0);
                accS = __builtin_amdgcn_mfma_f32_16x16x32_bf16(al, bh, accS, 0, 0, 0);
                accS = __builtin_amdgcn_mfma_f32_16x16x32_bf16(ah, bl, accS, 0, 0, 0);
            }
#pragma unroll
            for (int r = 0; r < 4; r++) {
                int row = quad * 4 + r;
                stp(hsH, hsL, (row << 8) + swz(row, nt * 16 + m), fmaxf(accS[r], 0.f));
            }
        }
    }
    __syncthreads();

    // ---- H3: cmlp GEMM2 (waves 0-3) ∥ smlp GEMM2 (wave 4) ----
    if (wid < 4) {
        f32x4 accD = (f32x4){0.f, 0.f, 0.f, 0.f};
        int row = wid * 16 + m;
#pragma unroll
        for (int kb = 0; kb < 6; kb++) {
            int c0 = kb * 32 + quad * 8;
            bf16x8 ah = *(const bf16x8*)&hcH[row * 192 + swz(row, c0)];
            bf16x8 al = *(const bf16x8*)&hcL[row * 192 + swz(row, c0)];
            int o = (kb << 9) + (lane << 3);
            bf16x8 bh = *(const bf16x8*)(c2h + o);
            bf16x8 bl = *(const bf16x8*)(c2l + o);
            accD = __builtin_amdgcn_mfma_f32_16x16x32_bf16(ah, bh, accD, 0, 0, 0);
            accD = __builtin_amdgcn_mfma_f32_16x16x32_bf16(al, bh, accD, 0, 0, 0);
            accD = __builtin_amdgcn_mfma_f32_16x16x32_bf16(ah, bl, accD, 0, 0, 0);
        }
#pragma unroll
        for (int r = 0; r < 4; r++) {
            int row2 = wid * 16 + quad * 4 + r;
            if (row2 < EC && m < 3)
                cmoL[row2 * 3 + m] = 1.f / (1.f + __expf(-accD[r]));
        }
    } else if (wid == 4) {
        f32x4 accT = (f32x4){0.f, 0.f, 0.f, 0.f};
#pragma unroll
        for (int kb = 0; kb < 8; kb++) {
            int c0 = kb * 32 + quad * 8;
            bf16x8 ah = *(const bf16x8*)&hsH[(m << 8) + swz(m, c0)];
            bf16x8 al = *(const bf16x8*)&hsL[(m << 8) + swz(m, c0)];
            int o = (kb << 9) + (lane << 3);
            bf16x8 bh = *(const bf16x8*)(s2h + o);
            bf16x8 bl = *(const bf16x8*)(s2l + o);
            accT = __builtin_amdgcn_mfma_f32_16x16x32_bf16(ah, bh, accT, 0, 0, 0);
            accT = __builtin_amdgcn_mfma_f32_16x16x32_bf16(al, bh, accT, 0, 0, 0);
            accT = __builtin_amdgcn_mfma_f32_16x16x32_bf16(ah, bl, accT, 0, 0, 0);
        }
#pragma unroll
        for (int r = 0; r < 4; r++) {
            int row = quad * 4 + r;
            if (row < NSW && m < 4)
                smoL[row * 4 + m] = 1.f / (1.f + __expf(-accT[r]));
        }
    }
    __syncthreads();

    // ---- final assembly ----
    if (t < 2 * MNE + VN) {
        float val;
        if (t < MNE) {
            val = (t < EC) ? cmoL[t * 3] - 0.5f : smoL[(t - EC) * 4 + 1] - 0.5f;
        } else if (t < MNE + VN) {
            int i = t - MNE;
            if (i == 0) {
                val = 1.0f;
            } else {
                float acc = 0.f;
                int c = incCnt[i];
                for (int q = 0; q < c; q++) {
                    int em = incM[i * 8 + q];
                    int mm = em >> 1, role = em & 1;
                    float vv = (mm < EC) ? 0.9f + 0.2f * cmoL[mm * 3 + 1 + role]
                                         : 0.9f + 0.2f * smoL[(mm - EC) * 4 + 2 + role];
                    acc += vv;
                }
                val = acc * dinvD[i];
            }
        } else {
            int mm = t - (MNE + VN);
            val = (mm < EC) ? 1.0f : smoL[(mm - EC) * 4];
        }
        size_t oidx = (size_t)b * (2 * MNE + VN) + t;
        if (fl) ((u16*)out_v)[oidx] = f2bf(val);
        else    ((float*)out_v)[oidx] = val;
    }
}

extern "C" void kernel_launch(void* const* d_in, const int* in_sizes, int n_in,
                              void* d_out, int out_size, void* d_ws, size_t ws_size,
                              hipStream_t stream) {
    const int* eA = (const int*)d_in[21];
    const int* eS = (const int*)d_in[22];

    float* pool = (float*)d_ws;
    float* ews     = pool;                       // 128
    float* dinv    = ews + 128;                  // 64
    float* dinvD   = dinv + 64;                  // 64
    int*   row_ptr = (int*)(dinvD + 64);         // 80
    int*   colp    = row_ptr + 80;               // 256
    int*   sw_eidx = colp + 256;                 // 16
    int*   incCnt  = sw_eidx + 16;               // 64
    int*   incM    = incCnt + 64;                // 512
    u16*   c1h = (u16*)(incM + 512);
    u16*   c1l = c1h + 36864;
    u16*   c2h = c1l + 36864;
    u16*   c2l = c2h + 3072;
    u16*   s1h = c2l + 3072;
    u16*   s1l = s1h + 65536;
    u16*   s2h = s1l + 65536;
    u16*   s2l = s2h + 4096;
    u16*   w0h = s2l + 4096;
    u16*   w0l = w0h + 8192;
    u16*   wlh = w0l + 8192;
    u16*   wll = wlh + 40960;

    CvtArgs ca;
    for (int i = 0; i < 21; i++) ca.src[i] = d_in[i];

    k_prep<<<1 + NPACK, 256, 0, stream>>>(ca, eA, eS,
                                          c1h, c1l, c2h, c2l, s1h, s1l, s2h, s2l,
                                          w0h, w0l, wlh, wll,
                                          ews, dinv, row_ptr, colp, sw_eidx,
                                          dinvD, incCnt, incM);

    k_main<<<BN, 1024, 0, stream>>>(d_in[0], (const u16*)d_in[1], eA, eS,
                                    ews, dinv, row_ptr, colp, sw_eidx,
                                    dinvD, incCnt, incM,
                                    w0h, w0l, wlh, wll,
                                    c1h, c1l, c2h, c2l, s1h, s1l, s2h, s2l,
                                    d_out);
}

// Round 5
// 169.064 us; speedup vs baseline: 1.0631x; 1.0631x over previous
//
#include <hip/hip_runtime.h>

#define BN 200
#define VN 64
#define HIDD 64
#define FINN 32
#define NSW 10
#define EC 63
#define MNE 73
#define NEDGE 146
#define NPACK 128

typedef unsigned short u16;
typedef unsigned int u32;
typedef __attribute__((ext_vector_type(8))) short bf16x8;
typedef __attribute__((ext_vector_type(4))) float f32x4;
typedef __attribute__((ext_vector_type(4))) u32 u32x4;

__device__ __forceinline__ float bfu(u16 u) { return __uint_as_float(((u32)u) << 16); }
__device__ __forceinline__ u16 f2bf(float f) {
    u32 x = __float_as_uint(f);
    u32 r = x + 0x7fffu + ((x >> 16) & 1u);
    return (u16)(r >> 16);
}
__device__ __forceinline__ float cvtv(const void* p, int i, int fl) {
    return fl ? bfu(((const u16*)p)[i]) : ((const float*)p)[i];
}

// u32-granular XOR swizzle (flips bits 2-4 -> keeps 16B alignment of 4-word blocks)
__device__ __forceinline__ int swzp(int row, int col) { return col ^ ((row & 7) << 2); }

// packed hi/lo bf16 in ONE u32 word: low16 = hi, high16 = lo. 1 DS op per access.
__device__ __forceinline__ float ldp1(const u32* P, int idx) {
    u32 v = P[idx];
    return __uint_as_float(v << 16) + __uint_as_float(v & 0xffff0000u);
}
__device__ __forceinline__ void stp1(u32* P, int idx, float f) {
    u16 h = f2bf(f);
    u16 l = f2bf(f - bfu(h));
    P[idx] = (u32)h | ((u32)l << 16);
}

// load 8-elem MFMA A-fragment (hi & lo planes) from packed u32 LDS, two b128 reads
__device__ __forceinline__ void ldfrag(const u32* P, int i0, int i1, bf16x8* ah, bf16x8* al) {
    u32x4 w0 = *(const u32x4*)&P[i0];
    u32x4 w1 = *(const u32x4*)&P[i1];
    union { bf16x8 v; u32 w[4]; } A, L;
    A.w[0] = (w0.x & 0xffffu) | (w0.y << 16);
    A.w[1] = (w0.z & 0xffffu) | (w0.w << 16);
    A.w[2] = (w1.x & 0xffffu) | (w1.y << 16);
    A.w[3] = (w1.z & 0xffffu) | (w1.w << 16);
    L.w[0] = (w0.x >> 16) | (w0.y & 0xffff0000u);
    L.w[1] = (w0.z >> 16) | (w0.w & 0xffff0000u);
    L.w[2] = (w1.x >> 16) | (w1.y & 0xffff0000u);
    L.w[3] = (w1.z >> 16) | (w1.w & 0xffff0000u);
    *ah = A.v;
    *al = L.v;
}

// ---- DPP wave64 sum-reduce (VALU pipe only, zero DS ops) ----
template <int CTRL>
__device__ __forceinline__ float dppadd(float x) {
    int v = __builtin_amdgcn_update_dpp(0, __float_as_int(x), CTRL, 0xf, 0xf, 1);
    return x + __int_as_float(v);
}
__device__ __forceinline__ float wtot64(float x) {
    x = dppadd<0x111>(x);   // row_shr:1
    x = dppadd<0x112>(x);   // row_shr:2
    x = dppadd<0x114>(x);   // row_shr:4
    x = dppadd<0x118>(x);   // row_shr:8
    x = dppadd<0x142>(x);   // row_bcast:15
    x = dppadd<0x143>(x);   // row_bcast:31  -> lane 63 holds total
    return __int_as_float(__builtin_amdgcn_readlane(__float_as_int(x), 63));
}
__device__ __forceinline__ float ln_dpp(float e) {
    float s1 = wtot64(e);
    float s2 = wtot64(e * e);
    float mean = s1 * 0.015625f;
    float var = fmaxf(s2 * 0.015625f - mean * mean, 0.f);
    return fmaxf((e - mean) * rsqrtf(var + 1e-5f), 0.f);
}

struct CvtArgs { const void* src[21]; };

// ======== prep (unchanged): block 0 = topology; blocks 1..NPACK = weight packing ========
__global__ __launch_bounds__(256) void k_prep(CvtArgs ca, const int* __restrict__ eA,
                                              const int* __restrict__ eS,
                                              u16* __restrict__ c1h, u16* __restrict__ c1l,
                                              u16* __restrict__ c2h, u16* __restrict__ c2l,
                                              u16* __restrict__ s1h, u16* __restrict__ s1l,
                                              u16* __restrict__ s2h, u16* __restrict__ s2l,
                                              u16* __restrict__ w0h, u16* __restrict__ w0l,
                                              u16* __restrict__ wlh, u16* __restrict__ wll,
                                              float* __restrict__ ews, float* __restrict__ dinv,
                                              int* __restrict__ row_ptr, int* __restrict__ colp,
                                              int* __restrict__ sw_eidx,
                                              float* __restrict__ dinvD, int* __restrict__ incCnt,
                                              int* __restrict__ incM) {
    int t = threadIdx.x;
    int fl = (((const u16*)ca.src[1])[1] == 0x3F80) ? 1 : 0;
    if (blockIdx.x == 0) {
        __shared__ unsigned char flagL[64 * 65];
        __shared__ float wsL[FINN * 64];
        __shared__ float emL[64];
        __shared__ int degL[64], rpS[65], colS[NEDGE + 16];
        __shared__ int eAL[2 * EC], eSL[2 * NSW];

        if (t < 2 * EC) eAL[t] = eA[t];
        if (t >= 128 && t < 128 + 2 * NSW) eSL[t - 128] = eS[t - 128];
        if (t >= 160 && t < 224) emL[t - 160] = cvtv(ca.src[3], t - 160, fl);
        for (int i = t; i < FINN * 64; i += 256) wsL[i] = cvtv(ca.src[4], i, fl);
        for (int i = t; i < 4096; i += 256) {
            float a = cvtv(ca.src[1], i, fl);
            float s = cvtv(ca.src[2], i, fl);
            int r = i >> 6, c = i & 63;
            flagL[r * 65 + c] = (unsigned char)(((a != 0.f || s != 0.f) ? 1 : 0) |
                                                ((s != 0.f) ? 2 : 0));
        }
        __syncthreads();

        if (t < 128) {
            int j = t >> 6, k = t & 63;
            float a = 0.f;
#pragma unroll
            for (int h = 0; h < FINN; h++) a += emL[j * FINN + h] * wsL[h * 64 + k];
            ews[(j << 6) + k] = a;
        }
        if (t < 64) {
            int d = 0;
#pragma unroll
            for (int w = 0; w < 64; w++) d += flagL[t * 65 + w] & 1;
            degL[t] = d;
            dinv[t] = 1.f / fmaxf((float)d, 1.f);
        }
        __syncthreads();
        if (t == 0) {
            int c = 0;
            for (int v = 0; v < 64; v++) { rpS[v] = c; c += degL[v]; }
            rpS[64] = c;
        }
        __syncthreads();
        if (t < 65) row_ptr[t] = rpS[t];
        if (t < 64) {
            int pos = rpS[t];
#pragma unroll
            for (int w = 0; w < 64; w++) {
                int f = flagL[t * 65 + w];
                if (f & 1) colS[pos++] = w | ((f & 2) ? 256 : 0) | (t << 16);
            }
        }
        __syncthreads();
        int tot = rpS[64];
        if (t < tot) colp[t] = colS[t];
        if (t < NSW) {
            int si = eSL[t], sj = eSL[NSW + t];
            int idx = 0;
            for (int e = rpS[si]; e < rpS[si + 1]; e++)
                if ((colS[e] & 255) == sj) idx = e;
            sw_eidx[t] = idx;
        }
        if (t < 64) {
            dinvD[t] = cvtv(ca.src[18], t * 64 + t, fl);
            int cnt = 0;
            for (int m = 0; m < MNE; m++) {
                int par = (m < EC) ? eAL[m] : eSL[m - EC];
                int chi = (m < EC) ? eAL[EC + m] : eSL[NSW + (m - EC)];
                if (par == t && cnt < 8) incM[t * 8 + cnt++] = (m << 1);
                if (chi == t && cnt < 8) incM[t * 8 + cnt++] = (m << 1) | 1;
            }
            incCnt[t] = cnt;
        }
    } else {
        const int T1 = 36864, T2 = T1 + 3072, T3 = T2 + 65536, T4 = T3 + 4096;
        const int T5 = T4 + 8192, TOT = T5 + 40960;
        for (int i = (blockIdx.x - 1) * 256 + t; i < TOT; i += NPACK * 256) {
            int idx = i;
            const void* src;
            u16 *dh, *dl;
            int K2, N2, nt, rem, loff = 0;
            if (idx < T1) {
                nt = idx / 3072; rem = idx - nt * 3072; src = ca.src[16];
                dh = c1h + idx; dl = c1l + idx; K2 = 192; N2 = 192;
            } else if (idx < T2) {
                idx -= T1; nt = 0; rem = idx; src = ca.src[17];
                dh = c2h + idx; dl = c2l + idx; K2 = 192; N2 = 3;
            } else if (idx < T3) {
                idx -= T2; nt = idx >> 12; rem = idx & 4095; src = ca.src[14];
                dh = s1h + idx; dl = s1l + idx; K2 = 256; N2 = 256;
            } else if (idx < T4) {
                idx -= T3; nt = 0; rem = idx; src = ca.src[15];
                dh = s2h + idx; dl = s2l + idx; K2 = 256; N2 = 4;
            } else if (idx < T5) {
                int j = idx - T4;
                int mt = j >> 11;             // 0=Wi 1=Wj 2=U 3=V  (src 5..8)
                int m2 = j & 2047;
                nt = m2 >> 9; rem = m2 & 511; src = ca.src[5 + mt];
                dh = w0h + j; dl = w0l + j; K2 = 32; N2 = 64;
            } else {
                int j = idx - T5;
                int l = j / 20480;
                int jj = j - l * 20480;
                int mt = jj >> 12;            // 0=Ws 1=Wi 2=Wj 3=U 4=V (src 9..13)
                int m2 = jj & 4095;
                nt = m2 >> 10; rem = m2 & 1023; src = ca.src[9 + mt];
                loff = l * 4096;
                dh = wlh + j; dl = wll + j; K2 = 64; N2 = 64;
            }
            int kb = rem >> 9, r8 = rem & 511, ln = r8 >> 3, jq = r8 & 7;
            int k = kb * 32 + ((ln >> 4) << 3) + jq;
            int n = nt * 16 + (ln & 15);
            float val = 0.f;
            if (n < N2 && k < K2) val = cvtv(src, loff + k * N2 + n, fl);
            u16 h = f2bf(val);
            *dh = h;
            *dl = f2bf(val - bfu(h));
        }
    }
}

#define XI 0
#define XJ 1
#define XU 2
#define XV 3

// ======== fused whole-model kernel ========
__global__ __launch_bounds__(1024) void k_main(
    const void* __restrict__ xraw, const u16* __restrict__ A_u16,
    const int* __restrict__ eA, const int* __restrict__ eS,
    const float* __restrict__ ews, const float* __restrict__ dinv,
    const int* __restrict__ row_ptr, const int* __restrict__ colp,
    const int* __restrict__ sw_eidx,
    const float* __restrict__ dinvD, const int* __restrict__ incCnt, const int* __restrict__ incM,
    const u16* __restrict__ w0h, const u16* __restrict__ w0l,
    const u16* __restrict__ wlh, const u16* __restrict__ wll,
    const u16* __restrict__ c1h, const u16* __restrict__ c1l,
    const u16* __restrict__ c2h, const u16* __restrict__ c2l,
    const u16* __restrict__ s1h, const u16* __restrict__ s1l,
    const u16* __restrict__ s2h, const u16* __restrict__ s2l,
    void* __restrict__ out_v)
{
    __shared__ __align__(16) u32 xP[64 * 64];          // node features, packed hi|lo
    __shared__ __align__(16) u32 sP[NEDGE * 64];       // edge states, packed hi|lo
    __shared__ __align__(16) float preL[NEDGE * 64];   // s@Ws pre-act / gate*xv (f32)
    __shared__ __align__(16) float tLs[4 * 64 * 64];   // xi/xj/xu/xv f32; heads: packed overlay
    __shared__ __align__(16) u32 xgPk[64];
    __shared__ float ewsL[128];
    __shared__ float dinvL[64];
    __shared__ int rpL[65];
    __shared__ int colL[NEDGE + 6];
    __shared__ int swLx[NSW];
    __shared__ int eALs[2 * EC], eSLs[2 * NSW];
    __shared__ float cmoL[EC * 3], smoL[NSW * 4];

    int b = blockIdx.x, t = threadIdx.x;
    int lane = t & 63, wid = t >> 6;          // 16 waves
    int m = lane & 15, quad = lane >> 4;
    int fl = (A_u16[1] == 0x3F80) ? 1 : 0;

    // ---- stage ----
    for (int i = t; i < 2048; i += 1024) {
        int r = i >> 5, c = i & 31;
        stp1(xP, (r << 6) + swzp(r, c), cvtv(xraw, b * 2048 + i, fl));
    }
    if (t < 128) ewsL[t] = ews[t];
    if (t < 64) dinvL[t] = dinv[t];
    if (t < 65) rpL[t] = row_ptr[t];
    if (t < NEDGE) colL[t] = colp[t];
    if (t < NSW) swLx[t] = sw_eidx[t];
    if (t >= 256 && t < 256 + 2 * EC) eALs[t - 256] = eA[t - 256];
    if (t >= 512 && t < 512 + 2 * NSW) eSLs[t - 512] = eS[t - 512];
    __syncthreads();

    // ---- layer 0 transforms: x(64x32) @ {Wi,Wj,U,V}(32x64) ----
    {
        int mat = wid >> 2, Mt = wid & 3;
        const u16* bhp = w0h + mat * 2048;
        const u16* blp = w0l + mat * 2048;
        int row = Mt * 16 + m;
        int c0 = quad * 8;
        bf16x8 ah, al;
        ldfrag(xP, (row << 6) + swzp(row, c0), (row << 6) + swzp(row, c0 + 4), &ah, &al);
        f32x4 acc[4];
#pragma unroll
        for (int nt = 0; nt < 4; nt++) acc[nt] = (f32x4){0.f, 0.f, 0.f, 0.f};
#pragma unroll
        for (int nt = 0; nt < 4; nt++) {
            int o = (nt << 9) + (lane << 3);
            bf16x8 bh = *(const bf16x8*)(bhp + o);
            bf16x8 bl = *(const bf16x8*)(blp + o);
            acc[nt] = __builtin_amdgcn_mfma_f32_16x16x32_bf16(ah, bh, acc[nt], 0, 0, 0);
            acc[nt] = __builtin_amdgcn_mfma_f32_16x16x32_bf16(al, bh, acc[nt], 0, 0, 0);
            acc[nt] = __builtin_amdgcn_mfma_f32_16x16x32_bf16(ah, bl, acc[nt], 0, 0, 0);
        }
#pragma unroll
        for (int nt = 0; nt < 4; nt++)
#pragma unroll
            for (int r = 0; r < 4; r++) {
                int orow = Mt * 16 + quad * 4 + r;
                tLs[mat * 4096 + (orow << 6) + swzp(orow, nt * 16 + m)] = acc[nt][r];
            }
    }
    __syncthreads();

    // ---- layer 0 B1: edge-parallel (LN via DPP, no shuffles) ----
    for (int e = wid; e < NEDGE; e += 32) {
        int e2i = e + 16;
        int has2 = (e2i < NEDGE);
        int eb2 = has2 ? e2i : e;
        int cpa = colL[e], cpb = colL[eb2];
        int wa = cpa & 255, va = (cpa >> 16) & 255;
        int wb = cpb & 255, vb = (cpb >> 16) & 255;
        int sia = (e << 6) + swzp(e, lane);
        int sib = (eb2 << 6) + swzp(eb2, lane);
        float eea = ewsL[(((cpa >> 8) & 1) << 6) + lane]
                  + tLs[XI * 4096 + (va << 6) + swzp(va, lane)]
                  + tLs[XJ * 4096 + (wa << 6) + swzp(wa, lane)];
        float eeb = ewsL[(((cpb >> 8) & 1) << 6) + lane]
                  + tLs[XI * 4096 + (vb << 6) + swzp(vb, lane)]
                  + tLs[XJ * 4096 + (wb << 6) + swzp(wb, lane)];
        float ha = ln_dpp(eea);
        float hb = ln_dpp(eeb);
        stp1(sP, sia, ha);
        preL[sia] = tLs[XV * 4096 + (wa << 6) + swzp(wa, lane)]
                  * __fdividef(1.f, 1.f + __expf(-ha));
        if (has2) {
            stp1(sP, sib, hb);
            preL[sib] = tLs[XV * 4096 + (wb << 6) + swzp(wb, lane)]
                      * __fdividef(1.f, 1.f + __expf(-hb));
        }
    }
    __syncthreads();

    // ---- layer 0 B2: per-v aggregation ----
    {
        int v0 = wid << 2;
        float mc0 = 0.f, mc1 = 0.f, mc2 = 0.f, mc3 = 0.f;
        for (int e = rpL[v0]; e < rpL[v0 + 1]; e++) mc0 += preL[(e << 6) + swzp(e, lane)];
        for (int e = rpL[v0 + 1]; e < rpL[v0 + 2]; e++) mc1 += preL[(e << 6) + swzp(e, lane)];
        for (int e = rpL[v0 + 2]; e < rpL[v0 + 3]; e++) mc2 += preL[(e << 6) + swzp(e, lane)];
        for (int e = rpL[v0 + 3]; e < rpL[v0 + 4]; e++) mc3 += preL[(e << 6) + swzp(e, lane)];
        float z0 = tLs[XU * 4096 + ((v0 + 0) << 6) + swzp(v0 + 0, lane)] + mc0 * dinvL[v0 + 0];
        float z1 = tLs[XU * 4096 + ((v0 + 1) << 6) + swzp(v0 + 1, lane)] + mc1 * dinvL[v0 + 1];
        float z2 = tLs[XU * 4096 + ((v0 + 2) << 6) + swzp(v0 + 2, lane)] + mc2 * dinvL[v0 + 2];
        float z3 = tLs[XU * 4096 + ((v0 + 3) << 6) + swzp(v0 + 3, lane)] + mc3 * dinvL[v0 + 3];
        float h0 = ln_dpp(z0), h1 = ln_dpp(z1), h2 = ln_dpp(z2), h3 = ln_dpp(z3);
        stp1(xP, ((v0 + 0) << 6) + swzp(v0 + 0, lane), h0);
        stp1(xP, ((v0 + 1) << 6) + swzp(v0 + 1, lane), h1);
        stp1(xP, ((v0 + 2) << 6) + swzp(v0 + 2, lane), h2);
        stp1(xP, ((v0 + 3) << 6) + swzp(v0 + 3, lane), h3);
    }
    __syncthreads();

    // ---- layers 1,2 ----
    for (int l = 0; l < 2; l++) {
        // (a) x-GEMMs (16 waves) + s-GEMM (40 units over 16 waves)
        {
            int mat = wid >> 2, Mt = wid & 3;
            const u16* bhp = wlh + l * 20480 + (mat + 1) * 4096;
            const u16* blp = wll + l * 20480 + (mat + 1) * 4096;
            int row = Mt * 16 + m;
            f32x4 acc[4];
#pragma unroll
            for (int nt = 0; nt < 4; nt++) acc[nt] = (f32x4){0.f, 0.f, 0.f, 0.f};
#pragma unroll
            for (int kb = 0; kb < 2; kb++) {
                int c0 = kb * 32 + quad * 8;
                bf16x8 ah, al;
                ldfrag(xP, (row << 6) + swzp(row, c0), (row << 6) + swzp(row, c0 + 4), &ah, &al);
#pragma unroll
                for (int nt = 0; nt < 4; nt++) {
                    int o = (((nt << 1) + kb) << 9) + (lane << 3);
                    bf16x8 bh = *(const bf16x8*)(bhp + o);
                    bf16x8 bl = *(const bf16x8*)(blp + o);
                    acc[nt] = __builtin_amdgcn_mfma_f32_16x16x32_bf16(ah, bh, acc[nt], 0, 0, 0);
                    acc[nt] = __builtin_amdgcn_mfma_f32_16x16x32_bf16(al, bh, acc[nt], 0, 0, 0);
                    acc[nt] = __builtin_amdgcn_mfma_f32_16x16x32_bf16(ah, bl, acc[nt], 0, 0, 0);
                }
            }
#pragma unroll
            for (int nt = 0; nt < 4; nt++)
#pragma unroll
                for (int r = 0; r < 4; r++) {
                    int orow = Mt * 16 + quad * 4 + r;
                    tLs[mat * 4096 + (orow << 6) + swzp(orow, nt * 16 + m)] = acc[nt][r];
                }

            const u16* sbh = wlh + l * 20480;   // Ws
            const u16* sbl = wll + l * 20480;
            for (int u = wid; u < 40; u += 16) {
                int rt = u >> 2, ntq = u & 3;
                int srow = rt * 16 + m;
                int ar = (srow > NEDGE - 1) ? (NEDGE - 1) : srow;
                f32x4 sacc = (f32x4){0.f, 0.f, 0.f, 0.f};
#pragma unroll
                for (int kb = 0; kb < 2; kb++) {
                    int c0 = kb * 32 + quad * 8;
                    bf16x8 ah, al;
                    ldfrag(sP, (ar << 6) + swzp(ar, c0), (ar << 6) + swzp(ar, c0 + 4), &ah, &al);
                    int o = (((ntq << 1) + kb) << 9) + (lane << 3);
                    bf16x8 bh = *(const bf16x8*)(sbh + o);
                    bf16x8 bl = *(const bf16x8*)(sbl + o);
                    sacc = __builtin_amdgcn_mfma_f32_16x16x32_bf16(ah, bh, sacc, 0, 0, 0);
                    sacc = __builtin_amdgcn_mfma_f32_16x16x32_bf16(al, bh, sacc, 0, 0, 0);
                    sacc = __builtin_amdgcn_mfma_f32_16x16x32_bf16(ah, bl, sacc, 0, 0, 0);
                }
#pragma unroll
                for (int r = 0; r < 4; r++) {
                    int orow = rt * 16 + quad * 4 + r;
                    if (orow < NEDGE)
                        preL[(orow << 6) + swzp(orow, ntq * 16 + m)] = sacc[r];
                }
            }
        }
        __syncthreads();

        // (b1) edge-parallel update
        for (int e = wid; e < NEDGE; e += 32) {
            int e2i = e + 16;
            int has2 = (e2i < NEDGE);
            int eb2 = has2 ? e2i : e;
            int cpa = colL[e], cpb = colL[eb2];
            int wa = cpa & 255, va = (cpa >> 16) & 255;
            int wb = cpb & 255, vb = (cpb >> 16) & 255;
            int sia = (e << 6) + swzp(e, lane);
            int sib = (eb2 << 6) + swzp(eb2, lane);
            float eea = preL[sia]
                      + tLs[XI * 4096 + (va << 6) + swzp(va, lane)]
                      + tLs[XJ * 4096 + (wa << 6) + swzp(wa, lane)];
            float eeb = preL[sib]
                      + tLs[XI * 4096 + (vb << 6) + swzp(vb, lane)]
                      + tLs[XJ * 4096 + (wb << 6) + swzp(wb, lane)];
            float ha = ln_dpp(eea);
            float hb = ln_dpp(eeb);
            float souta = ldp1(sP, sia) + ha;
            float soutb = ldp1(sP, sib) + hb;
            stp1(sP, sia, souta);
            preL[sia] = tLs[XV * 4096 + (wa << 6) + swzp(wa, lane)]
                      * __fdividef(1.f, 1.f + __expf(-souta));
            if (has2) {
                stp1(sP, sib, soutb);
                preL[sib] = tLs[XV * 4096 + (wb << 6) + swzp(wb, lane)]
                          * __fdividef(1.f, 1.f + __expf(-soutb));
            }
        }
        __syncthreads();

        // (b2) per-v aggregation + node update (+ xg partial on last layer)
        {
            int v0 = wid << 2;
            float mc0 = 0.f, mc1 = 0.f, mc2 = 0.f, mc3 = 0.f;
            for (int e = rpL[v0]; e < rpL[v0 + 1]; e++) mc0 += preL[(e << 6) + swzp(e, lane)];
            for (int e = rpL[v0 + 1]; e < rpL[v0 + 2]; e++) mc1 += preL[(e << 6) + swzp(e, lane)];
            for (int e = rpL[v0 + 2]; e < rpL[v0 + 3]; e++) mc2 += preL[(e << 6) + swzp(e, lane)];
            for (int e = rpL[v0 + 3]; e < rpL[v0 + 4]; e++) mc3 += preL[(e << 6) + swzp(e, lane)];
            float z0 = tLs[XU * 4096 + ((v0 + 0) << 6) + swzp(v0 + 0, lane)] + mc0 * dinvL[v0 + 0];
            float z1 = tLs[XU * 4096 + ((v0 + 1) << 6) + swzp(v0 + 1, lane)] + mc1 * dinvL[v0 + 1];
            float z2 = tLs[XU * 4096 + ((v0 + 2) << 6) + swzp(v0 + 2, lane)] + mc2 * dinvL[v0 + 2];
            float z3 = tLs[XU * 4096 + ((v0 + 3) << 6) + swzp(v0 + 3, lane)] + mc3 * dinvL[v0 + 3];
            float h0 = ln_dpp(z0), h1 = ln_dpp(z1), h2 = ln_dpp(z2), h3 = ln_dpp(z3);
            int i0 = ((v0 + 0) << 6) + swzp(v0 + 0, lane);
            int i1 = ((v0 + 1) << 6) + swzp(v0 + 1, lane);
            int i2 = ((v0 + 2) << 6) + swzp(v0 + 2, lane);
            int i3 = ((v0 + 3) << 6) + swzp(v0 + 3, lane);
            float x0 = ldp1(xP, i0) + h0;
            float x1 = ldp1(xP, i1) + h1;
            float x2 = ldp1(xP, i2) + h2;
            float x3 = ldp1(xP, i3) + h3;
            stp1(xP, i0, x0);
            stp1(xP, i1, x1);
            stp1(xP, i2, x2);
            stp1(xP, i3, x3);
            if (l == 1) tLs[(wid << 6) + lane] = x0 + x1 + x2 + x3;   // xg partial
        }
        __syncthreads();
    }

    // ---- xg final ----
    if (t < 64) {
        float s = 0.f;
#pragma unroll
        for (int i = 0; i < 16; i++) s += tLs[(i << 6) + t];
        stp1(xgPk, t, s);
    }
    __syncthreads();

    // ======== heads ========
    u32* hcP = (u32*)tLs;           // 64 x 192 packed
    u32* hsP = (u32*)tLs + 12288;   // 16 x 256 packed

    // ---- H2: cmlp GEMM1 (waves 0-11) ∥ smlp GEMM1 (waves 12-15) ----
    if (wid < 12) {
        int Mt = wid & 3, ntg = wid >> 2;
        int e = Mt * 16 + m; if (e > 62) e = 62;
        int ai = eALs[e], aj = eALs[EC + e];
        f32x4 acc[4];
#pragma unroll
        for (int j = 0; j < 4; j++) acc[j] = (f32x4){0.f, 0.f, 0.f, 0.f};
#pragma unroll
        for (int kb = 0; kb < 6; kb++) {
            int k = kb * 32 + quad * 8;
            bf16x8 ah, al;
            if (k < 64) {
                ldfrag(xP, (ai << 6) + swzp(ai, k), (ai << 6) + swzp(ai, k + 4), &ah, &al);
            } else if (k < 128) {
                int c = k - 64;
                ldfrag(xP, (aj << 6) + swzp(aj, c), (aj << 6) + swzp(aj, c + 4), &ah, &al);
            } else {
                int c = k - 128;
                ldfrag(xgPk, c, c + 4, &ah, &al);
            }
#pragma unroll
            for (int j = 0; j < 4; j++) {
                int nt = ntg * 4 + j;
                int o = ((nt * 6 + kb) << 9) + (lane << 3);
                bf16x8 bh = *(const bf16x8*)(c1h + o);
                bf16x8 bl = *(const bf16x8*)(c1l + o);
                acc[j] = __builtin_amdgcn_mfma_f32_16x16x32_bf16(ah, bh, acc[j], 0, 0, 0);
                acc[j] = __builtin_amdgcn_mfma_f32_16x16x32_bf16(al, bh, acc[j], 0, 0, 0);
                acc[j] = __builtin_amdgcn_mfma_f32_16x16x32_bf16(ah, bl, acc[j], 0, 0, 0);
            }
        }
#pragma unroll
        for (int j = 0; j < 4; j++) {
            int nt = ntg * 4 + j;
#pragma unroll
            for (int r = 0; r < 4; r++) {
                int row = Mt * 16 + quad * 4 + r;
                stp1(hcP, row * 192 + swzp(row, nt * 16 + m), fmaxf(acc[j][r], 0.f));
            }
        }
    } else {
        int e2 = (m > 9) ? 9 : m;
        int si = eSLs[e2], sj = eSLs[NSW + e2];
        int sw = swLx[e2];
        f32x4 accS[4];
#pragma unroll
        for (int j = 0; j < 4; j++) accS[j] = (f32x4){0.f, 0.f, 0.f, 0.f};
#pragma unroll
        for (int kb = 0; kb < 8; kb++) {
            int k = kb * 32 + quad * 8;
            bf16x8 ah, al;
            if (k < 64) {
                ldfrag(sP, (sw << 6) + swzp(sw, k), (sw << 6) + swzp(sw, k + 4), &ah, &al);
            } else if (k < 128) {
                int c = k - 64;
                ldfrag(xP, (si << 6) + swzp(si, c), (si << 6) + swzp(si, c + 4), &ah, &al);
            } else if (k < 192) {
                int c = k - 128;
                ldfrag(xP, (sj << 6) + swzp(sj, c), (sj << 6) + swzp(sj, c + 4), &ah, &al);
            } else {
                int c = k - 192;
                ldfrag(xgPk, c, c + 4, &ah, &al);
            }
#pragma unroll
            for (int j = 0; j < 4; j++) {
                int nt = (wid - 12) * 4 + j;
                int o = ((nt * 8 + kb) << 9) + (lane << 3);
                bf16x8 bh = *(const bf16x8*)(s1h + o);
                bf16x8 bl = *(const bf16x8*)(s1l + o);
                accS[j] = __builtin_amdgcn_mfma_f32_16x16x32_bf16(ah, bh, accS[j], 0, 0, 0);
                accS[j] = __builtin_amdgcn_mfma_f32_16x16x32_bf16(al, bh, accS[j], 0, 0, 0);
                accS[j] = __builtin_amdgcn_mfma_f32_16x16x32_bf16(ah, bl, accS[j], 0, 0, 0);
            }
        }
#pragma unroll
        for (int j = 0; j < 4; j++) {
            int nt = (wid - 12) * 4 + j;
#pragma unroll
            for (int r = 0; r < 4; r++) {
                int row = quad * 4 + r;
                stp1(hsP, (row << 8) + swzp(row, nt * 16 + m), fmaxf(accS[j][r], 0.f));
            }
        }
    }
    __syncthreads();

    // ---- H3: cmlp GEMM2 (waves 0-3) ∥ smlp GEMM2 (wave 4) ----
    if (wid < 4) {
        f32x4 accD = (f32x4){0.f, 0.f, 0.f, 0.f};
        int row = wid * 16 + m;
#pragma unroll
        for (int kb = 0; kb < 6; kb++) {
            int c0 = kb * 32 + quad * 8;
            bf16x8 ah, al;
            ldfrag(hcP, row * 192 + swzp(row, c0), row * 192 + swzp(row, c0 + 4), &ah, &al);
            int o = (kb << 9) + (lane << 3);
            bf16x8 bh = *(const bf16x8*)(c2h + o);
            bf16x8 bl = *(const bf16x8*)(c2l + o);
            accD = __builtin_amdgcn_mfma_f32_16x16x32_bf16(ah, bh, accD, 0, 0, 0);
            accD = __builtin_amdgcn_mfma_f32_16x16x32_bf16(al, bh, accD, 0, 0, 0);
            accD = __builtin_amdgcn_mfma_f32_16x16x32_bf16(ah, bl, accD, 0, 0, 0);
        }
#pragma unroll
        for (int r = 0; r < 4; r++) {
            int row2 = wid * 16 + quad * 4 + r;
            if (row2 < EC && m < 3)
                cmoL[row2 * 3 + m] = 1.f / (1.f + __expf(-accD[r]));
        }
    } else if (wid == 4) {
        f32x4 accT = (f32x4){0.f, 0.f, 0.f, 0.f};
#pragma unroll
        for (int kb = 0; kb < 8; kb++) {
            int c0 = kb * 32 + quad * 8;
            bf16x8 ah, al;
            ldfrag(hsP, (m << 8) + swzp(m, c0), (m << 8) + swzp(m, c0 + 4), &ah, &al);
            int o = (kb << 9) + (lane << 3);
            bf16x8 bh = *(const bf16x8*)(s2h + o);
            bf16x8 bl = *(const bf16x8*)(s2l + o);
            accT = __builtin_amdgcn_mfma_f32_16x16x32_bf16(ah, bh, accT, 0, 0, 0);
            accT = __builtin_amdgcn_mfma_f32_16x16x32_bf16(al, bh, accT, 0, 0, 0);
            accT = __builtin_amdgcn_mfma_f32_16x16x32_bf16(ah, bl, accT, 0, 0, 0);
        }
#pragma unroll
        for (int r = 0; r < 4; r++) {
            int row = quad * 4 + r;
            if (row < NSW && m < 4)
                smoL[row * 4 + m] = 1.f / (1.f + __expf(-accT[r]));
        }
    }
    __syncthreads();

    // ---- final assembly ----
    if (t < 2 * MNE + VN) {
        float val;
        if (t < MNE) {
            val = (t < EC) ? cmoL[t * 3] - 0.5f : smoL[(t - EC) * 4 + 1] - 0.5f;
        } else if (t < MNE + VN) {
            int i = t - MNE;
            if (i == 0) {
                val = 1.0f;
            } else {
                float acc = 0.f;
                int c = incCnt[i];
                for (int q = 0; q < c; q++) {
                    int em = incM[i * 8 + q];
                    int mm = em >> 1, role = em & 1;
                    float vv = (mm < EC) ? 0.9f + 0.2f * cmoL[mm * 3 + 1 + role]
                                         : 0.9f + 0.2f * smoL[(mm - EC) * 4 + 2 + role];
                    acc += vv;
                }
                val = acc * dinvD[i];
            }
        } else {
            int mm = t - (MNE + VN);
            val = (mm < EC) ? 1.0f : smoL[(mm - EC) * 4];
        }
        size_t oidx = (size_t)b * (2 * MNE + VN) + t;
        if (fl) ((u16*)out_v)[oidx] = f2bf(val);
        else    ((float*)out_v)[oidx] = val;
    }
}

extern "C" void kernel_launch(void* const* d_in, const int* in_sizes, int n_in,
                              void* d_out, int out_size, void* d_ws, size_t ws_size,
                              hipStream_t stream) {
    const int* eA = (const int*)d_in[21];
    const int* eS = (const int*)d_in[22];

    float* pool = (float*)d_ws;
    float* ews     = pool;                       // 128
    float* dinv    = ews + 128;                  // 64
    float* dinvD   = dinv + 64;                  // 64
    int*   row_ptr = (int*)(dinvD + 64);         // 80
    int*   colp    = row_ptr + 80;               // 256
    int*   sw_eidx = colp + 256;                 // 16
    int*   incCnt  = sw_eidx + 16;               // 64
    int*   incM    = incCnt + 64;                // 512
    u16*   c1h = (u16*)(incM + 512);
    u16*   c1l = c1h + 36864;
    u16*   c2h = c1l + 36864;
    u16*   c2l = c2h + 3072;
    u16*   s1h = c2l + 3072;
    u16*   s1l = s1h + 65536;
    u16*   s2h = s1l + 65536;
    u16*   s2l = s2h + 4096;
    u16*   w0h = s2l + 4096;
    u16*   w0l = w0h + 8192;
    u16*   wlh = w0l + 8192;
    u16*   wll = wlh + 40960;

    CvtArgs ca;
    for (int i = 0; i < 21; i++) ca.src[i] = d_in[i];

    k_prep<<<1 + NPACK, 256, 0, stream>>>(ca, eA, eS,
                                          c1h, c1l, c2h, c2l, s1h, s1l, s2h, s2l,
                                          w0h, w0l, wlh, wll,
                                          ews, dinv, row_ptr, colp, sw_eidx,
                                          dinvD, incCnt, incM);

    k_main<<<BN, 1024, 0, stream>>>(d_in[0], (const u16*)d_in[1], eA, eS,
                                    ews, dinv, row_ptr, colp, sw_eidx,
                                    dinvD, incCnt, incM,
                                    w0h, w0l, wlh, wll,
                                    c1h, c1l, c2h, c2l, s1h, s1l, s2h, s2l,
                                    d_out);
}